// Round 14
// baseline (46.241 us; speedup 1.0000x reference)
//
#include <hip/hip_runtime.h>
#include <hip/hip_bf16.h>

typedef __attribute__((ext_vector_type(4)))  float f32x4;
typedef __attribute__((ext_vector_type(16))) float f32x16;
typedef __attribute__((ext_vector_type(8)))  short bf16x8;
typedef __attribute__((ext_vector_type(4)))  unsigned u32x4;
typedef __attribute__((ext_vector_type(2)))  unsigned u32x2;

#define NEG_INF_F (-1000000000.0f)

// native bf16 RNE converts -> compiler emits v_cvt_pk_bf16_f32
__device__ inline unsigned pkbf(float a, float b) {
    union { __hip_bfloat16 h; unsigned short u; } x, y;
    x.h = __float2bfloat16(a);
    y.h = __float2bfloat16(b);
    return (unsigned)x.u | ((unsigned)y.u << 16);
}

// ---------- prep1: per-b compaction of valid (mask!=0) key indices ----------
__global__ __launch_bounds__(1024) void aoa_prep_kernel(
    const int* __restrict__ maskp,
    int* __restrict__ vidx, float* __restrict__ padmask, int* __restrict__ nvalid)
{
    const int b   = blockIdx.x;
    const int tid = threadIdx.x;
    const int lane = tid & 63;

    const int m = maskp[b * 1024 + tid] ? 1 : 0;
    unsigned long long bal = __ballot(m);
    const int wpre = __popcll(bal & ((1ull << lane) - 1ull));

    __shared__ int wsum[16], woff[16];
    if (lane == 63) wsum[tid >> 6] = wpre + m;
    __syncthreads();
    if (tid < 16) {
        int off = 0;
        for (int i = 0; i < tid; ++i) off += wsum[i];
        woff[tid] = off;
    }
    __syncthreads();
    const int pos = woff[tid >> 6] + wpre;
    const int nv  = woff[15] + wsum[15];

    if (m) vidx[b * 1024 + pos] = tid;
    if (tid >= nv) vidx[b * 1024 + tid] = 0;     // pad -> row 0; killed by padmask
    padmask[b * 1024 + tid] = (tid < nv) ? 0.0f : NEG_INF_F;
    if (tid == 0) nvalid[b] = nv;
}

// ---------- prep2: gather + convert: Kc[bh][pos][d] bf16, Vtc[bh][d][pos] bf16 ----------
// grid (64 bh, 16 chunk), 256 thr (R11-verified transpose pattern + index gather).
__global__ __launch_bounds__(256) void aoa_gather_kernel(
    const float* __restrict__ keyp, const float* __restrict__ v2,
    const int* __restrict__ vidx,
    short* __restrict__ Kc, short* __restrict__ Vtc)
{
    const int bh  = blockIdx.x;
    const int c   = blockIdx.y;
    const int tid = threadIdx.x;
    const int b   = bh >> 3;
    const size_t base = (size_t)bh * 65536;

    __shared__ short T[64][72];

    const int k    = tid >> 2;          // 0..63 (position within chunk)
    const int dseg = (tid & 3) << 4;    // 0,16,32,48
    const int pos  = c * 64 + k;
    const int idx  = vidx[b * 1024 + pos];

    {
        const f32x4* ks = (const f32x4*)(keyp + base + (size_t)idx * 64 + dseg);
        f32x4 a0 = ks[0], a1 = ks[1], a2 = ks[2], a3 = ks[3];
        u32x4 w0 = (u32x4){pkbf(a0[0],a0[1]), pkbf(a0[2],a0[3]), pkbf(a1[0],a1[1]), pkbf(a1[2],a1[3])};
        u32x4 w1 = (u32x4){pkbf(a2[0],a2[1]), pkbf(a2[2],a2[3]), pkbf(a3[0],a3[1]), pkbf(a3[2],a3[3])};
        short* kd = Kc + base + (size_t)pos * 64 + dseg;
        *(u32x4*)kd = w0; *(u32x4*)(kd + 8) = w1;

        const f32x4* vs = (const f32x4*)(v2 + base + (size_t)idx * 64 + dseg);
        f32x4 b0 = vs[0], b1 = vs[1], b2 = vs[2], b3 = vs[3];
        u32x4 t0 = (u32x4){pkbf(b0[0],b0[1]), pkbf(b0[2],b0[3]), pkbf(b1[0],b1[1]), pkbf(b1[2],b1[3])};
        u32x4 t1 = (u32x4){pkbf(b2[0],b2[1]), pkbf(b2[2],b2[3]), pkbf(b3[0],b3[1]), pkbf(b3[2],b3[3])};
        *(u32x4*)&T[k][dseg]     = t0;
        *(u32x4*)&T[k][dseg + 8] = t1;
    }
    __syncthreads();
    {
        const int d    = tid >> 2;
        const int kseg = (tid & 3) << 4;
        short tmp[16];
        #pragma unroll
        for (int i = 0; i < 16; ++i) tmp[i] = T[kseg + i][d];
        short* vd = Vtc + base + (size_t)d * 1024 + c * 64 + kseg;
        *(u32x4*)vd       = *(u32x4*)&tmp[0];
        *(u32x4*)(vd + 8) = *(u32x4*)&tmp[8];
    }
}

// ---------- attention: R8 hot loop over NT~9 compacted tiles, bf16 staging ----------
// Block = 8 warps x 32 q = 256 q. Grid (64 bh, 4 qt) = 1 block/CU.
// mfma_f32_32x32x16_bf16:
//   A[m][k]: m=lane&31, k=(lane>>5)*8+j ; B[k][n]: n=lane&31, k=(lane>>5)*8+j
//   C[m][n]: n=lane&31, m=crow(r,h)=(r&3)+8*(r>>2)+4*(lane>>5)
__global__ __launch_bounds__(512) void aoa_attn_kernel(
    const float* __restrict__ gv,
    const float* __restrict__ q2,
    const float* __restrict__ keyp,
    const float* __restrict__ v1,
    const float* __restrict__ W,
    const float* __restrict__ bch,
    const short* __restrict__ Kc,
    const short* __restrict__ Vtc,
    const float* __restrict__ padmask,
    const int*   __restrict__ nvalid,
    float* __restrict__ out)
{
    constexpr int S = 1024, D = 64;
    const int bh  = blockIdx.x;
    const int qt  = blockIdx.y;
    const int b   = bh >> 3;
    const int tid = threadIdx.x;
    const int wid = tid >> 6;
    const int lane = tid & 63;
    const int l31 = lane & 31;
    const int h   = lane >> 5;

    float* out_attn = out + 512;
    if (bh == 0 && qt == 0) out[tid] = gv[tid];

    __shared__ float pmL[S];               // 0 or NEG_INF (compacted order)
    __shared__ short Klds[2][64][72];      // [buf][key][d], 144B stride
    __shared__ short Vt[2][64][72];        // [buf][d][key]
    __shared__ float Lw[8][32];            // per-warp 1/l per q

    for (int i = tid; i < S; i += 512)
        pmL[i] = padmask[b * S + i];

    const int nv = nvalid[b];
    const int NT = (nv + 63) >> 6;

    const size_t base = (size_t)bh * S * D;
    const float* Qp  = q2   + base;
    const float* Kp  = keyp + base;
    const float* V1p = v1   + base;
    const short* Kcb = Kc  + base;         // [pos][d] bf16
    const short* Vcb = Vtc + base;         // [d][pos] bf16

    const int q0   = qt * 256 + wid * 32;
    const int qrow = q0 + l31;

    // Q B-fragments: bq[ds][j] = Q[qrow][ds*16 + h*8 + j]
    bf16x8 bq[4];
    #pragma unroll
    for (int ds = 0; ds < 4; ++ds) {
        const f32x4* p = (const f32x4*)(Qp + (size_t)qrow * D + ds * 16 + h * 8);
        f32x4 x0 = p[0], x1 = p[1];
        u32x4 u = (u32x4){pkbf(x0[0], x0[1]), pkbf(x0[2], x0[3]),
                          pkbf(x1[0], x1[1]), pkbf(x1[2], x1[3])};
        bq[ds] = *(bf16x8*)&u;
    }

    f32x16 acc_o[2];
    #pragma unroll
    for (int dh = 0; dh < 2; ++dh)
        #pragma unroll
        for (int r = 0; r < 16; ++r) acc_o[dh][r] = 0.0f;

    float m_run = -1e30f, l_run = 0.0f;
    const float SC = 0.125f * 1.4426950408889634f;   // D^-0.5 * log2(e)

    // staging indices (512 threads): one 16B bf16 load each for K and Vt
    const int kk   = tid >> 3;          // K row 0..63
    const int d0   = (tid & 7) << 3;    // K d-offset (8 bf16)
    const int vd   = tid & 63;          // Vt d-row
    const int vk0  = (tid >> 6) << 3;   // Vt key chunk = wid*8

    // prologue: tile 0 -> regs -> buf 0
    u32x4 kw = *(const u32x4*)(Kcb + (size_t)kk * 64 + d0);
    u32x4 vw = *(const u32x4*)(Vcb + (size_t)vd * 1024 + vk0);
    *(u32x4*)&Klds[0][kk][d0] = kw;
    *(u32x4*)&Vt[0][vd][vk0]  = vw;
    int cur = 0;

    for (int t = 0; t < NT; ++t) {
        const int kt = t * 64;
        __syncthreads();   // buf[cur] + pmL visible; buf[cur^1] free

        if (t < NT - 1) {   // issue next tile's loads; land under compute
            kw = *(const u32x4*)(Kcb + (size_t)(kt + 64 + kk) * 64 + d0);
            vw = *(const u32x4*)(Vcb + (size_t)vd * 1024 + kt + 64 + vk0);
        }

        // ---- QK^T half 0 (keys kt+0..31) ----
        f32x16 a0;
        #pragma unroll
        for (int r = 0; r < 16; ++r) a0[r] = 0.0f;
        #pragma unroll
        for (int ds = 0; ds < 4; ++ds) {
            bf16x8 ak = *(const bf16x8*)&Klds[cur][l31][ds * 16 + h * 8];
            a0 = __builtin_amdgcn_mfma_f32_32x32x16_bf16(ak, bq[ds], a0, 0, 0, 0);
        }
        // ---- QK^T half 1 — issued BEFORE softmax(h0) ----
        f32x16 a1;
        #pragma unroll
        for (int r = 0; r < 16; ++r) a1[r] = 0.0f;
        #pragma unroll
        for (int ds = 0; ds < 4; ++ds) {
            bf16x8 ak = *(const bf16x8*)&Klds[cur][32 + l31][ds * 16 + h * 8];
            a1 = __builtin_amdgcn_mfma_f32_32x32x16_bf16(ak, bq[ds], a1, 0, 0, 0);
        }

        // ---- softmax half 0 (VALU; overlaps QK h1) ----
        unsigned w0[8];
        {
            float s[16], tmax = -1e30f;
            #pragma unroll
            for (int g = 0; g < 4; ++g) {
                f32x4 mk = *(const f32x4*)&pmL[kt + g * 8 + h * 4];
                #pragma unroll
                for (int j = 0; j < 4; ++j) {
                    float val = fmaf(a0[g * 4 + j], SC, mk[j]);
                    s[g * 4 + j] = val;
                    tmax = fmaxf(tmax, val);
                }
            }
            tmax = fmaxf(tmax, __shfl_xor(tmax, 32));
            if (__any(tmax > m_run + 8.0f)) {   // defer-max (T13)
                float mnew = fmaxf(m_run, tmax);
                float r = __builtin_amdgcn_exp2f(m_run - mnew);
                l_run *= r;
                #pragma unroll
                for (int dh = 0; dh < 2; ++dh)
                    #pragma unroll
                    for (int r2 = 0; r2 < 16; ++r2) acc_o[dh][r2] *= r;
                m_run = mnew;
            }
            float ps0 = 0.f, ps1 = 0.f;
            #pragma unroll
            for (int i = 0; i < 8; ++i) {
                float p0 = __builtin_amdgcn_exp2f(s[2 * i]     - m_run);
                float p1 = __builtin_amdgcn_exp2f(s[2 * i + 1] - m_run);
                ps0 += p0; ps1 += p1;
                w0[i] = pkbf(p0, p1);
            }
            float psum = ps0 + ps1;
            psum += __shfl_xor(psum, 32);
            l_run += psum;
        }

        // ---- PV half 0 ----
        #pragma unroll
        for (int t2 = 0; t2 < 2; ++t2) {
            u32x2 r0 = __builtin_amdgcn_permlane32_swap(w0[t2 * 4 + 0], w0[t2 * 4 + 2], false, false);
            u32x2 r1 = __builtin_amdgcn_permlane32_swap(w0[t2 * 4 + 1], w0[t2 * 4 + 3], false, false);
            u32x4 ua = (u32x4){r0[0], r1[0], r0[1], r1[1]};
            bf16x8 pa = *(bf16x8*)&ua;
            #pragma unroll
            for (int dh = 0; dh < 2; ++dh) {
                bf16x8 bv = *(const bf16x8*)&Vt[cur][dh * 32 + l31][t2 * 16 + h * 8];
                acc_o[dh] = __builtin_amdgcn_mfma_f32_32x32x16_bf16(pa, bv, acc_o[dh], 0, 0, 0);
            }
        }

        // ---- softmax half 1 (VALU; overlaps PV h0) ----
        unsigned w1[8];
        {
            float s[16], tmax = -1e30f;
            #pragma unroll
            for (int g = 0; g < 4; ++g) {
                f32x4 mk = *(const f32x4*)&pmL[kt + 32 + g * 8 + h * 4];
                #pragma unroll
                for (int j = 0; j < 4; ++j) {
                    float val = fmaf(a1[g * 4 + j], SC, mk[j]);
                    s[g * 4 + j] = val;
                    tmax = fmaxf(tmax, val);
                }
            }
            tmax = fmaxf(tmax, __shfl_xor(tmax, 32));
            if (__any(tmax > m_run + 8.0f)) {
                float mnew = fmaxf(m_run, tmax);
                float r = __builtin_amdgcn_exp2f(m_run - mnew);
                l_run *= r;
                #pragma unroll
                for (int dh = 0; dh < 2; ++dh)
                    #pragma unroll
                    for (int r2 = 0; r2 < 16; ++r2) acc_o[dh][r2] *= r;
                m_run = mnew;
            }
            float ps0 = 0.f, ps1 = 0.f;
            #pragma unroll
            for (int i = 0; i < 8; ++i) {
                float p0 = __builtin_amdgcn_exp2f(s[2 * i]     - m_run);
                float p1 = __builtin_amdgcn_exp2f(s[2 * i + 1] - m_run);
                ps0 += p0; ps1 += p1;
                w1[i] = pkbf(p0, p1);
            }
            float psum = ps0 + ps1;
            psum += __shfl_xor(psum, 32);
            l_run += psum;
        }

        // ---- PV half 1 ----
        #pragma unroll
        for (int t2 = 0; t2 < 2; ++t2) {
            u32x2 r0 = __builtin_amdgcn_permlane32_swap(w1[t2 * 4 + 0], w1[t2 * 4 + 2], false, false);
            u32x2 r1 = __builtin_amdgcn_permlane32_swap(w1[t2 * 4 + 1], w1[t2 * 4 + 3], false, false);
            u32x4 ua = (u32x4){r0[0], r1[0], r0[1], r1[1]};
            bf16x8 pa = *(bf16x8*)&ua;
            #pragma unroll
            for (int dh = 0; dh < 2; ++dh) {
                bf16x8 bv = *(const bf16x8*)&Vt[cur][dh * 32 + l31][32 + t2 * 16 + h * 8];
                acc_o[dh] = __builtin_amdgcn_mfma_f32_32x32x16_bf16(pa, bv, acc_o[dh], 0, 0, 0);
            }
        }

        if (t < NT - 1) {   // write next tile into alternate buffer
            *(u32x4*)&Klds[cur ^ 1][kk][d0] = kw;
            *(u32x4*)&Vt[cur ^ 1][vd][vk0]  = vw;
        }
        cur ^= 1;
    }

    // ---- channel gate: gate[q][e] = sum_d am[q][d]*W[e][d], same C layout as O ----
    f32x16 acc_g[2];
    #pragma unroll
    for (int eh = 0; eh < 2; ++eh)
        #pragma unroll
        for (int r = 0; r < 16; ++r) acc_g[eh][r] = 0.0f;

    bf16x8 bam[4];
    #pragma unroll
    for (int ds = 0; ds < 4; ++ds) {
        const f32x4* p1 = (const f32x4*)(V1p + (size_t)qrow * D + ds * 16 + h * 8);
        const f32x4* pk = (const f32x4*)(Kp  + (size_t)qrow * D + ds * 16 + h * 8);
        f32x4 a0 = p1[0], a1 = p1[1], c0 = pk[0], c1 = pk[1];
        u32x4 u = (u32x4){pkbf(a0[0]*c0[0], a0[1]*c0[1]), pkbf(a0[2]*c0[2], a0[3]*c0[3]),
                          pkbf(a1[0]*c1[0], a1[1]*c1[1]), pkbf(a1[2]*c1[2], a1[3]*c1[3])};
        bam[ds] = *(bf16x8*)&u;
    }
    #pragma unroll
    for (int eh = 0; eh < 2; ++eh) {
        #pragma unroll
        for (int ds = 0; ds < 4; ++ds) {
            const f32x4* pw = (const f32x4*)(W + (size_t)(eh * 32 + l31) * D + ds * 16 + h * 8);
            f32x4 x0 = pw[0], x1 = pw[1];
            u32x4 u = (u32x4){pkbf(x0[0], x0[1]), pkbf(x0[2], x0[3]),
                              pkbf(x1[0], x1[1]), pkbf(x1[2], x1[3])};
            bf16x8 bw = *(bf16x8*)&u;
            acc_g[eh] = __builtin_amdgcn_mfma_f32_32x32x16_bf16(bam[ds], bw, acc_g[eh], 0, 0, 0);
        }
    }

    // ---- epilogue: out = (O/l) * sigmoid(gate + b) ----
    Lw[wid][l31] = 1.0f / l_run;
    __builtin_amdgcn_wave_barrier();
    const float bv0 = bch[l31], bv1 = bch[32 + l31];
    #pragma unroll
    for (int dh = 0; dh < 2; ++dh) {
        const float bc = dh ? bv1 : bv0;
        #pragma unroll
        for (int r = 0; r < 16; ++r) {
            const int ql = (r & 3) + 8 * (r >> 2) + 4 * h;   // crow(r,h)
            float invl = Lw[wid][ql];
            float o = acc_o[dh][r] * invl;
            float z = acc_g[dh][r] + bc;
            float gate = 1.0f / (1.0f + __expf(-z));
            out_attn[base + (size_t)(q0 + ql) * D + dh * 32 + l31] = o * gate;
        }
    }
}

extern "C" void kernel_launch(void* const* d_in, const int* in_sizes, int n_in,
                              void* d_out, int out_size, void* d_ws, size_t ws_size,
                              hipStream_t stream) {
    const float* gv   = (const float*)d_in[0];
    const float* q2   = (const float*)d_in[1];
    const float* keyp = (const float*)d_in[2];
    const int*   mask = (const int*)  d_in[3];
    const float* v1   = (const float*)d_in[4];
    const float* v2   = (const float*)d_in[5];
    const float* W    = (const float*)d_in[6];
    const float* bch  = (const float*)d_in[7];
    float* out = (float*)d_out;

    short* Kc      = (short*)d_ws;                    // 64*1024*64 bf16 = 8.4 MB
    short* Vtc     = Kc + 64ull * 1024 * 64;          // 8.4 MB
    int*   vidx    = (int*)(Vtc + 64ull * 1024 * 64); // 32 KB
    float* padmask = (float*)(vidx + 8 * 1024);       // 32 KB
    int*   nvalid  = (int*)(padmask + 8 * 1024);      // 32 B   (total ~16.9 MB)

    aoa_prep_kernel<<<8, 1024, 0, stream>>>(mask, vidx, padmask, nvalid);

    dim3 ggrid(64, 16);
    aoa_gather_kernel<<<ggrid, 256, 0, stream>>>(keyp, v2, vidx, Kc, Vtc);

    dim3 grid(64, 4);   // (b*h, 256-row q-tile) = 256 blocks = 1/CU
    aoa_attn_kernel<<<grid, 512, 0, stream>>>(gv, q2, keyp, v1, W, bch,
                                              Kc, Vtc, padmask, nvalid, out);
}

// Round 15
// 41.722 us; speedup vs baseline: 1.1083x; 1.1083x over previous
//
#include <hip/hip_runtime.h>
#include <hip/hip_bf16.h>

typedef __attribute__((ext_vector_type(4)))  float f32x4;
typedef __attribute__((ext_vector_type(16))) float f32x16;
typedef __attribute__((ext_vector_type(8)))  short bf16x8;
typedef __attribute__((ext_vector_type(4)))  unsigned u32x4;
typedef __attribute__((ext_vector_type(2)))  unsigned u32x2;
typedef __attribute__((ext_vector_type(4)))  int i32x4;

#define NEG_INF_F (-1000000000.0f)

// native bf16 RNE converts -> compiler emits v_cvt_pk_bf16_f32
__device__ inline unsigned pkbf(float a, float b) {
    union { __hip_bfloat16 h; unsigned short u; } x, y;
    x.h = __float2bfloat16(a);
    y.h = __float2bfloat16(b);
    return (unsigned)x.u | ((unsigned)y.u << 16);
}

// ---------- prep1: per-b compaction of valid (mask!=0) key indices ----------
__global__ __launch_bounds__(1024) void aoa_prep_kernel(
    const int* __restrict__ maskp,
    int* __restrict__ vidx, float* __restrict__ padmask, int* __restrict__ nvalid)
{
    const int b   = blockIdx.x;
    const int tid = threadIdx.x;
    const int lane = tid & 63;

    const int m = maskp[b * 1024 + tid] ? 1 : 0;
    unsigned long long bal = __ballot(m);
    const int wpre = __popcll(bal & ((1ull << lane) - 1ull));

    __shared__ int wsum[16], woff[16];
    if (lane == 63) wsum[tid >> 6] = wpre + m;
    __syncthreads();
    if (tid < 16) {
        int off = 0;
        for (int i = 0; i < tid; ++i) off += wsum[i];
        woff[tid] = off;
    }
    __syncthreads();
    const int pos = woff[tid >> 6] + wpre;
    const int nv  = woff[15] + wsum[15];

    if (m) vidx[b * 1024 + pos] = tid;
    if (tid >= nv) vidx[b * 1024 + tid] = 0;     // pad -> row 0; killed by padmask
    padmask[b * 1024 + tid] = (tid < nv) ? 0.0f : NEG_INF_F;
    if (tid == 0) nvalid[b] = nv;
}

// ---------- attention: R13 structure, 128 keys per barrier period ----------
// Block = 8 warps x 32 q = 256 q. Grid (64 bh, 4 qt) = 1 block/CU.
// mfma_f32_32x32x16_bf16:
//   A[m][k]: m=lane&31, k=(lane>>5)*8+j ; B[k][n]: n=lane&31, k=(lane>>5)*8+j
//   C[m][n]: n=lane&31, m=crow(r,h)=(r&3)+8*(r>>2)+4*(lane>>5)
// QK^T swapped -> lane holds q, 32 keys in regs; softmax in-lane; P via
// cvt_pk + permlane32_swap; PV B-operand from transposed Vt LDS; dbuf;
// per-64-key half-pipelining (QK h1 before SM h0; SM h1 between PV h0/h1).
// R15: NT2 = ceil(nv/128) barrier periods, each staging 128 gathered keys.
__global__ __launch_bounds__(512) void aoa_attn_kernel(
    const float* __restrict__ gv,
    const float* __restrict__ q2,
    const float* __restrict__ keyp,
    const float* __restrict__ v1,
    const float* __restrict__ v2,
    const float* __restrict__ W,
    const float* __restrict__ bch,
    const int*   __restrict__ vidx,
    const float* __restrict__ padmask,
    const int*   __restrict__ nvalid,
    float* __restrict__ out)
{
    constexpr int S = 1024, D = 64;
    const int bh  = blockIdx.x;
    const int qt  = blockIdx.y;
    const int b   = bh >> 3;
    const int tid = threadIdx.x;
    const int wid = tid >> 6;
    const int lane = tid & 63;
    const int l31 = lane & 31;
    const int h   = lane >> 5;

    float* out_attn = out + 512;
    if (bh == 0 && qt == 0) out[tid] = gv[tid];

    __shared__ float pmL[S];                // 0 or NEG_INF (compacted order)
    __shared__ int   vidxL[S];              // gathered key ids
    __shared__ short Klds[2][128][72];      // [buf][key][d], 144B stride
    __shared__ short Vt[2][64][136];        // [buf][d][key(128)]
    __shared__ float Lw[8][32];             // per-warp 1/l per q

    for (int i = tid; i < S; i += 512) {
        pmL[i]   = padmask[b * S + i];
        vidxL[i] = vidx[b * S + i];
    }

    const int nv  = nvalid[b];
    const int NT2 = (nv + 127) >> 7;        // 128-key periods

    const size_t base = (size_t)bh * S * D;
    const float* Qp  = q2   + base;
    const float* Kp  = keyp + base;
    const float* V1p = v1   + base;
    const float* V2p = v2   + base;

    const int q0   = qt * 256 + wid * 32;
    const int qrow = q0 + l31;

    // Q B-fragments: bq[ds][j] = Q[qrow][ds*16 + h*8 + j]
    bf16x8 bq[4];
    #pragma unroll
    for (int ds = 0; ds < 4; ++ds) {
        const f32x4* p = (const f32x4*)(Qp + (size_t)qrow * D + ds * 16 + h * 8);
        f32x4 x0 = p[0], x1 = p[1];
        u32x4 u = (u32x4){pkbf(x0[0], x0[1]), pkbf(x0[2], x0[3]),
                          pkbf(x1[0], x1[1]), pkbf(x1[2], x1[3])};
        bq[ds] = *(bf16x8*)&u;
    }

    f32x16 acc_o[2];
    #pragma unroll
    for (int dh = 0; dh < 2; ++dh)
        #pragma unroll
        for (int r = 0; r < 16; ++r) acc_o[dh][r] = 0.0f;

    float m_run = -1e30f, l_run = 0.0f;
    const float SC = 0.125f * 1.4426950408889634f;   // D^-0.5 * log2(e)

    // staging indices (512 threads)
    const int kk   = tid >> 3;          // K row-in-half 0..63
    const int d0   = (tid & 7) << 3;    // K d-offset
    const int vd   = tid & 63;          // Vt d-row
    const int kr0  = (tid >> 6) << 3;   // Vt key chunk-in-half = wid*8

    __syncthreads();                    // vidxL/pmL ready

    // prologue: period 0 (128 keys) -> buf 0
    {
        #pragma unroll
        for (int hh = 0; hh < 2; ++hh) {
            const int kidx = vidxL[hh * 64 + kk];
            const f32x4* src = (const f32x4*)(Kp + (size_t)kidx * D + d0);
            f32x4 a = src[0], c = src[1];
            *(u32x4*)&Klds[0][hh * 64 + kk][d0] =
                (u32x4){pkbf(a[0], a[1]), pkbf(a[2], a[3]), pkbf(c[0], c[1]), pkbf(c[2], c[3])};
            i32x4 i0 = *(const i32x4*)&vidxL[hh * 64 + kr0];
            i32x4 i1 = *(const i32x4*)&vidxL[hh * 64 + kr0 + 4];
            float vvp[8];
            vvp[0] = V2p[(size_t)i0[0] * D + vd]; vvp[1] = V2p[(size_t)i0[1] * D + vd];
            vvp[2] = V2p[(size_t)i0[2] * D + vd]; vvp[3] = V2p[(size_t)i0[3] * D + vd];
            vvp[4] = V2p[(size_t)i1[0] * D + vd]; vvp[5] = V2p[(size_t)i1[1] * D + vd];
            vvp[6] = V2p[(size_t)i1[2] * D + vd]; vvp[7] = V2p[(size_t)i1[3] * D + vd];
            *(u32x4*)&Vt[0][vd][hh * 64 + kr0] =
                (u32x4){pkbf(vvp[0], vvp[1]), pkbf(vvp[2], vvp[3]),
                        pkbf(vvp[4], vvp[5]), pkbf(vvp[6], vvp[7])};
        }
    }
    int cur = 0;

    for (int it = 0; it < NT2; ++it) {
        const int kt = it * 128;
        __syncthreads();   // buf[cur] visible; buf[cur^1] free

        // ---- prefetch period it+1 (4 K-rows + 16 V scalars; land under compute) ----
        f32x4 nk[4];
        float nvv[16];
        if (it < NT2 - 1) {
            #pragma unroll
            for (int hh = 0; hh < 2; ++hh) {
                const int kidx = vidxL[kt + 128 + hh * 64 + kk];
                const f32x4* src = (const f32x4*)(Kp + (size_t)kidx * D + d0);
                nk[hh * 2]     = src[0];
                nk[hh * 2 + 1] = src[1];
                i32x4 i0 = *(const i32x4*)&vidxL[kt + 128 + hh * 64 + kr0];
                i32x4 i1 = *(const i32x4*)&vidxL[kt + 128 + hh * 64 + kr0 + 4];
                nvv[hh * 8 + 0] = V2p[(size_t)i0[0] * D + vd];
                nvv[hh * 8 + 1] = V2p[(size_t)i0[1] * D + vd];
                nvv[hh * 8 + 2] = V2p[(size_t)i0[2] * D + vd];
                nvv[hh * 8 + 3] = V2p[(size_t)i0[3] * D + vd];
                nvv[hh * 8 + 4] = V2p[(size_t)i1[0] * D + vd];
                nvv[hh * 8 + 5] = V2p[(size_t)i1[1] * D + vd];
                nvv[hh * 8 + 6] = V2p[(size_t)i1[2] * D + vd];
                nvv[hh * 8 + 7] = V2p[(size_t)i1[3] * D + vd];
            }
        }

        // ---- compute two 64-key halves ----
        #pragma unroll
        for (int hh = 0; hh < 2; ++hh) {
            const int kb  = kt + hh * 64;      // pmL base for this half
            const int kr  = hh * 64;           // LDS row/col base

            // QK^T half 0 (keys kr+0..31)
            f32x16 a0;
            #pragma unroll
            for (int r = 0; r < 16; ++r) a0[r] = 0.0f;
            #pragma unroll
            for (int ds = 0; ds < 4; ++ds) {
                bf16x8 ak = *(const bf16x8*)&Klds[cur][kr + l31][ds * 16 + h * 8];
                a0 = __builtin_amdgcn_mfma_f32_32x32x16_bf16(ak, bq[ds], a0, 0, 0, 0);
            }
            // QK^T half 1 — issued BEFORE softmax(h0)
            f32x16 a1;
            #pragma unroll
            for (int r = 0; r < 16; ++r) a1[r] = 0.0f;
            #pragma unroll
            for (int ds = 0; ds < 4; ++ds) {
                bf16x8 ak = *(const bf16x8*)&Klds[cur][kr + 32 + l31][ds * 16 + h * 8];
                a1 = __builtin_amdgcn_mfma_f32_32x32x16_bf16(ak, bq[ds], a1, 0, 0, 0);
            }

            // softmax half 0 (VALU; overlaps QK h1)
            unsigned w0[8];
            {
                float s[16], tmax = -1e30f;
                #pragma unroll
                for (int g = 0; g < 4; ++g) {
                    f32x4 mk = *(const f32x4*)&pmL[kb + g * 8 + h * 4];
                    #pragma unroll
                    for (int j = 0; j < 4; ++j) {
                        float val = fmaf(a0[g * 4 + j], SC, mk[j]);
                        s[g * 4 + j] = val;
                        tmax = fmaxf(tmax, val);
                    }
                }
                tmax = fmaxf(tmax, __shfl_xor(tmax, 32));
                if (__any(tmax > m_run + 8.0f)) {   // defer-max (T13)
                    float mnew = fmaxf(m_run, tmax);
                    float r = __builtin_amdgcn_exp2f(m_run - mnew);
                    l_run *= r;
                    #pragma unroll
                    for (int dh = 0; dh < 2; ++dh)
                        #pragma unroll
                        for (int r2 = 0; r2 < 16; ++r2) acc_o[dh][r2] *= r;
                    m_run = mnew;
                }
                float ps0 = 0.f, ps1 = 0.f;
                #pragma unroll
                for (int i = 0; i < 8; ++i) {
                    float p0 = __builtin_amdgcn_exp2f(s[2 * i]     - m_run);
                    float p1 = __builtin_amdgcn_exp2f(s[2 * i + 1] - m_run);
                    ps0 += p0; ps1 += p1;
                    w0[i] = pkbf(p0, p1);
                }
                float psum = ps0 + ps1;
                psum += __shfl_xor(psum, 32);
                l_run += psum;
            }

            // PV half 0
            #pragma unroll
            for (int t2 = 0; t2 < 2; ++t2) {
                u32x2 r0 = __builtin_amdgcn_permlane32_swap(w0[t2 * 4 + 0], w0[t2 * 4 + 2], false, false);
                u32x2 r1 = __builtin_amdgcn_permlane32_swap(w0[t2 * 4 + 1], w0[t2 * 4 + 3], false, false);
                u32x4 ua = (u32x4){r0[0], r1[0], r0[1], r1[1]};
                bf16x8 pa = *(bf16x8*)&ua;
                #pragma unroll
                for (int dh = 0; dh < 2; ++dh) {
                    bf16x8 bv = *(const bf16x8*)&Vt[cur][dh * 32 + l31][kr + t2 * 16 + h * 8];
                    acc_o[dh] = __builtin_amdgcn_mfma_f32_32x32x16_bf16(pa, bv, acc_o[dh], 0, 0, 0);
                }
            }

            // softmax half 1 (VALU; overlaps PV h0)
            unsigned w1[8];
            {
                float s[16], tmax = -1e30f;
                #pragma unroll
                for (int g = 0; g < 4; ++g) {
                    f32x4 mk = *(const f32x4*)&pmL[kb + 32 + g * 8 + h * 4];
                    #pragma unroll
                    for (int j = 0; j < 4; ++j) {
                        float val = fmaf(a1[g * 4 + j], SC, mk[j]);
                        s[g * 4 + j] = val;
                        tmax = fmaxf(tmax, val);
                    }
                }
                tmax = fmaxf(tmax, __shfl_xor(tmax, 32));
                if (__any(tmax > m_run + 8.0f)) {
                    float mnew = fmaxf(m_run, tmax);
                    float r = __builtin_amdgcn_exp2f(m_run - mnew);
                    l_run *= r;
                    #pragma unroll
                    for (int dh = 0; dh < 2; ++dh)
                        #pragma unroll
                        for (int r2 = 0; r2 < 16; ++r2) acc_o[dh][r2] *= r;
                    m_run = mnew;
                }
                float ps0 = 0.f, ps1 = 0.f;
                #pragma unroll
                for (int i = 0; i < 8; ++i) {
                    float p0 = __builtin_amdgcn_exp2f(s[2 * i]     - m_run);
                    float p1 = __builtin_amdgcn_exp2f(s[2 * i + 1] - m_run);
                    ps0 += p0; ps1 += p1;
                    w1[i] = pkbf(p0, p1);
                }
                float psum = ps0 + ps1;
                psum += __shfl_xor(psum, 32);
                l_run += psum;
            }

            // PV half 1
            #pragma unroll
            for (int t2 = 0; t2 < 2; ++t2) {
                u32x2 r0 = __builtin_amdgcn_permlane32_swap(w1[t2 * 4 + 0], w1[t2 * 4 + 2], false, false);
                u32x2 r1 = __builtin_amdgcn_permlane32_swap(w1[t2 * 4 + 1], w1[t2 * 4 + 3], false, false);
                u32x4 ua = (u32x4){r0[0], r1[0], r0[1], r1[1]};
                bf16x8 pa = *(bf16x8*)&ua;
                #pragma unroll
                for (int dh = 0; dh < 2; ++dh) {
                    bf16x8 bv = *(const bf16x8*)&Vt[cur][dh * 32 + l31][kr + 32 + t2 * 16 + h * 8];
                    acc_o[dh] = __builtin_amdgcn_mfma_f32_32x32x16_bf16(pa, bv, acc_o[dh], 0, 0, 0);
                }
            }
        }

        // ---- tail: write period it+1 into alternate buffer ----
        if (it < NT2 - 1) {
            #pragma unroll
            for (int hh = 0; hh < 2; ++hh) {
                f32x4 a = nk[hh * 2], c = nk[hh * 2 + 1];
                *(u32x4*)&Klds[cur ^ 1][hh * 64 + kk][d0] =
                    (u32x4){pkbf(a[0], a[1]), pkbf(a[2], a[3]), pkbf(c[0], c[1]), pkbf(c[2], c[3])};
                *(u32x4*)&Vt[cur ^ 1][vd][hh * 64 + kr0] =
                    (u32x4){pkbf(nvv[hh * 8 + 0], nvv[hh * 8 + 1]), pkbf(nvv[hh * 8 + 2], nvv[hh * 8 + 3]),
                            pkbf(nvv[hh * 8 + 4], nvv[hh * 8 + 5]), pkbf(nvv[hh * 8 + 6], nvv[hh * 8 + 7])};
            }
        }
        cur ^= 1;
    }

    // ---- channel gate: gate[q][e] = sum_d am[q][d]*W[e][d], same C layout as O ----
    f32x16 acc_g[2];
    #pragma unroll
    for (int eh = 0; eh < 2; ++eh)
        #pragma unroll
        for (int r = 0; r < 16; ++r) acc_g[eh][r] = 0.0f;

    bf16x8 bam[4];
    #pragma unroll
    for (int ds = 0; ds < 4; ++ds) {
        const f32x4* p1 = (const f32x4*)(V1p + (size_t)qrow * D + ds * 16 + h * 8);
        const f32x4* pk = (const f32x4*)(Kp  + (size_t)qrow * D + ds * 16 + h * 8);
        f32x4 a0 = p1[0], a1 = p1[1], c0 = pk[0], c1 = pk[1];
        u32x4 u = (u32x4){pkbf(a0[0]*c0[0], a0[1]*c0[1]), pkbf(a0[2]*c0[2], a0[3]*c0[3]),
                          pkbf(a1[0]*c1[0], a1[1]*c1[1]), pkbf(a1[2]*c1[2], a1[3]*c1[3])};
        bam[ds] = *(bf16x8*)&u;
    }
    #pragma unroll
    for (int eh = 0; eh < 2; ++eh) {
        #pragma unroll
        for (int ds = 0; ds < 4; ++ds) {
            const f32x4* pw = (const f32x4*)(W + (size_t)(eh * 32 + l31) * D + ds * 16 + h * 8);
            f32x4 x0 = pw[0], x1 = pw[1];
            u32x4 u = (u32x4){pkbf(x0[0], x0[1]), pkbf(x0[2], x0[3]),
                              pkbf(x1[0], x1[1]), pkbf(x1[2], x1[3])};
            bf16x8 bw = *(bf16x8*)&u;
            acc_g[eh] = __builtin_amdgcn_mfma_f32_32x32x16_bf16(bam[ds], bw, acc_g[eh], 0, 0, 0);
        }
    }

    // ---- epilogue: out = (O/l) * sigmoid(gate + b) ----
    Lw[wid][l31] = 1.0f / l_run;
    __builtin_amdgcn_wave_barrier();
    const float bv0 = bch[l31], bv1 = bch[32 + l31];
    #pragma unroll
    for (int dh = 0; dh < 2; ++dh) {
        const float bc = dh ? bv1 : bv0;
        #pragma unroll
        for (int r = 0; r < 16; ++r) {
            const int ql = (r & 3) + 8 * (r >> 2) + 4 * h;   // crow(r,h)
            float invl = Lw[wid][ql];
            float o = acc_o[dh][r] * invl;
            float z = acc_g[dh][r] + bc;
            float gate = 1.0f / (1.0f + __expf(-z));
            out_attn[base + (size_t)(q0 + ql) * D + dh * 32 + l31] = o * gate;
        }
    }
}

extern "C" void kernel_launch(void* const* d_in, const int* in_sizes, int n_in,
                              void* d_out, int out_size, void* d_ws, size_t ws_size,
                              hipStream_t stream) {
    const float* gv   = (const float*)d_in[0];
    const float* q2   = (const float*)d_in[1];
    const float* keyp = (const float*)d_in[2];
    const int*   mask = (const int*)  d_in[3];
    const float* v1   = (const float*)d_in[4];
    const float* v2   = (const float*)d_in[5];
    const float* W    = (const float*)d_in[6];
    const float* bch  = (const float*)d_in[7];
    float* out = (float*)d_out;

    int*   vidx    = (int*)d_ws;                   // 8*1024 int
    float* padmask = (float*)(vidx + 8 * 1024);    // 8*1024 f32
    int*   nvalid  = (int*)(padmask + 8 * 1024);   // 8 int

    aoa_prep_kernel<<<8, 1024, 0, stream>>>(mask, vidx, padmask, nvalid);

    dim3 grid(64, 4);   // (b*h, 256-row q-tile) = 256 blocks = 1/CU
    aoa_attn_kernel<<<grid, 512, 0, stream>>>(gv, q2, keyp, v1, v2, W, bch,
                                              vidx, padmask, nvalid, out);
}

// Round 17
// 41.326 us; speedup vs baseline: 1.1189x; 1.0096x over previous
//
#include <hip/hip_runtime.h>
#include <hip/hip_bf16.h>

typedef __attribute__((ext_vector_type(4)))  float f32x4;
typedef __attribute__((ext_vector_type(16))) float f32x16;
typedef __attribute__((ext_vector_type(8)))  short bf16x8;
typedef __attribute__((ext_vector_type(4)))  unsigned u32x4;
typedef __attribute__((ext_vector_type(2)))  unsigned u32x2;

#define NEG_INF_F (-1000000000.0f)

// native bf16 RNE converts -> compiler emits v_cvt_pk_bf16_f32
__device__ inline unsigned pkbf(float a, float b) {
    union { __hip_bfloat16 h; unsigned short u; } x, y;
    x.h = __float2bfloat16(a);
    y.h = __float2bfloat16(b);
    return (unsigned)x.u | ((unsigned)y.u << 16);
}

// ---------- prep1: per-b compaction of valid (mask!=0) key indices ----------
__global__ __launch_bounds__(1024) void aoa_prep_kernel(
    const int* __restrict__ maskp,
    int* __restrict__ vidx, float* __restrict__ padmask, int* __restrict__ nvalid)
{
    const int b   = blockIdx.x;
    const int tid = threadIdx.x;
    const int lane = tid & 63;

    const int m = maskp[b * 1024 + tid] ? 1 : 0;
    unsigned long long bal = __ballot(m);
    const int wpre = __popcll(bal & ((1ull << lane) - 1ull));

    __shared__ int wsum[16], woff[16];
    if (lane == 63) wsum[tid >> 6] = wpre + m;
    __syncthreads();
    if (tid < 16) {
        int off = 0;
        for (int i = 0; i < tid; ++i) off += wsum[i];
        woff[tid] = off;
    }
    __syncthreads();
    const int pos = woff[tid >> 6] + wpre;
    const int nv  = woff[15] + wsum[15];

    if (m) vidx[b * 1024 + pos] = tid;
    if (tid >= nv) vidx[b * 1024 + tid] = 0;     // pad -> row 0; killed by padmask
    padmask[b * 1024 + tid] = (tid < nv) ? 0.0f : NEG_INF_F;
    if (tid == 0) nvalid[b] = nv;
}

// ---------- attention: R8 structure + gathered keys (NT ~ nv/64 tiles) ----------
// Block = 8 warps x 32 q = 256 q. Grid (64 bh, 4 qt) = 1 block/CU.
// mfma_f32_32x32x16_bf16:
//   A[m][k]: m=lane&31, k=(lane>>5)*8+j ; B[k][n]: n=lane&31, k=(lane>>5)*8+j
//   C[m][n]: n=lane&31, m=crow(r,h)=(r&3)+8*(r>>2)+4*(lane>>5)
// QK^T swapped -> lane holds q, 32 keys in regs; softmax in-lane; P via
// cvt_pk + permlane32_swap; PV B-operand from transposed Vt LDS; dbuf (T14);
// intra-tile half-pipelining (QK h1 before SM h0; SM h1 between PV h0/h1).
__global__ __launch_bounds__(512) void aoa_attn_kernel(
    const float* __restrict__ gv,
    const float* __restrict__ q2,
    const float* __restrict__ keyp,
    const float* __restrict__ v1,
    const float* __restrict__ v2,
    const float* __restrict__ W,
    const float* __restrict__ bch,
    const int*   __restrict__ vidx,
    const float* __restrict__ padmask,
    const int*   __restrict__ nvalid,
    float* __restrict__ out)
{
    constexpr int S = 1024, D = 64;
    const int bh  = blockIdx.x;
    const int qt  = blockIdx.y;
    const int b   = bh >> 3;
    const int tid = threadIdx.x;
    const int wid = tid >> 6;
    const int lane = tid & 63;
    const int l31 = lane & 31;
    const int h   = lane >> 5;

    float* out_attn = out + 512;
    if (bh == 0 && qt == 0) out[tid] = gv[tid];

    __shared__ float pmL[S];               // 0 or NEG_INF (compacted order)
    __shared__ int   vidxL[S];             // gathered key ids
    __shared__ short Klds[2][64][72];      // [buf][key][d], 144B stride
    __shared__ short Vt[2][64][72];        // [buf][d][key]
    __shared__ float Lw[8][32];            // per-warp 1/l per q

    for (int i = tid; i < S; i += 512) {
        pmL[i]   = padmask[b * S + i];
        vidxL[i] = vidx[b * S + i];
    }

    const int nv = nvalid[b];
    const int NT = (nv + 63) >> 6;

    const size_t base = (size_t)bh * S * D;
    const float* Qp  = q2   + base;
    const float* Kp  = keyp + base;
    const float* V1p = v1   + base;
    const float* V2p = v2   + base;

    const int q0   = qt * 256 + wid * 32;
    const int qrow = q0 + l31;

    // Q B-fragments: bq[ds][j] = Q[qrow][ds*16 + h*8 + j]
    bf16x8 bq[4];
    #pragma unroll
    for (int ds = 0; ds < 4; ++ds) {
        const f32x4* p = (const f32x4*)(Qp + (size_t)qrow * D + ds * 16 + h * 8);
        f32x4 x0 = p[0], x1 = p[1];
        u32x4 u = (u32x4){pkbf(x0[0], x0[1]), pkbf(x0[2], x0[3]),
                          pkbf(x1[0], x1[1]), pkbf(x1[2], x1[3])};
        bq[ds] = *(bf16x8*)&u;
    }

    f32x16 acc_o[2];
    #pragma unroll
    for (int dh = 0; dh < 2; ++dh)
        #pragma unroll
        for (int r = 0; r < 16; ++r) acc_o[dh][r] = 0.0f;

    float m_run = -1e30f, l_run = 0.0f;
    const float SC = 0.125f * 1.4426950408889634f;   // D^-0.5 * log2(e)

    // staging indices (512 threads)
    const int kk   = tid >> 3;          // K row 0..63
    const int d0   = (tid & 7) << 3;    // K d-offset
    const int dcol = tid & 63;          // Vt d-column
    const int kr0  = (tid >> 6) << 3;   // Vt key chunk = wid*8

    __syncthreads();                    // vidxL/pmL ready

    // prologue: tile 0 (gathered) -> regs -> buf 0
    f32x4 kA, kB;
    float vv[8];
    {
        const f32x4* src = (const f32x4*)(Kp + (size_t)vidxL[kk] * D + d0);
        kA = src[0]; kB = src[1];
        #pragma unroll
        for (int i = 0; i < 8; ++i) vv[i] = V2p[(size_t)vidxL[kr0 + i] * D + dcol];
    }
    *(u32x4*)&Klds[0][kk][d0] = (u32x4){pkbf(kA[0], kA[1]), pkbf(kA[2], kA[3]),
                                        pkbf(kB[0], kB[1]), pkbf(kB[2], kB[3])};
    *(u32x4*)&Vt[0][dcol][kr0] = (u32x4){pkbf(vv[0], vv[1]), pkbf(vv[2], vv[3]),
                                         pkbf(vv[4], vv[5]), pkbf(vv[6], vv[7])};
    int cur = 0;

    for (int t = 0; t < NT; ++t) {
        const int kt = t * 64;
        __syncthreads();   // buf[cur] visible; buf[cur^1] free

        if (t < NT - 1) {   // issue next tile's loads; land under compute
            const f32x4* src = (const f32x4*)(Kp + (size_t)vidxL[kt + 64 + kk] * D + d0);
            kA = src[0]; kB = src[1];
            #pragma unroll
            for (int i = 0; i < 8; ++i) vv[i] = V2p[(size_t)vidxL[kt + 64 + kr0 + i] * D + dcol];
        }

        // ---- QK^T half 0 (gathered keys kt+0..31) ----
        f32x16 a0;
        #pragma unroll
        for (int r = 0; r < 16; ++r) a0[r] = 0.0f;
        #pragma unroll
        for (int ds = 0; ds < 4; ++ds) {
            bf16x8 ak = *(const bf16x8*)&Klds[cur][l31][ds * 16 + h * 8];
            a0 = __builtin_amdgcn_mfma_f32_32x32x16_bf16(ak, bq[ds], a0, 0, 0, 0);
        }
        // ---- QK^T half 1 — issued BEFORE softmax(h0) ----
        f32x16 a1;
        #pragma unroll
        for (int r = 0; r < 16; ++r) a1[r] = 0.0f;
        #pragma unroll
        for (int ds = 0; ds < 4; ++ds) {
            bf16x8 ak = *(const bf16x8*)&Klds[cur][32 + l31][ds * 16 + h * 8];
            a1 = __builtin_amdgcn_mfma_f32_32x32x16_bf16(ak, bq[ds], a1, 0, 0, 0);
        }

        // ---- softmax half 0 (VALU; overlaps QK h1) ----
        unsigned w0[8];
        {
            float s[16], tmax = -1e30f;
            #pragma unroll
            for (int g = 0; g < 4; ++g) {
                f32x4 mk = *(const f32x4*)&pmL[kt + g * 8 + h * 4];
                #pragma unroll
                for (int j = 0; j < 4; ++j) {
                    float val = fmaf(a0[g * 4 + j], SC, mk[j]);
                    s[g * 4 + j] = val;
                    tmax = fmaxf(tmax, val);
                }
            }
            tmax = fmaxf(tmax, __shfl_xor(tmax, 32));
            if (__any(tmax > m_run + 8.0f)) {   // defer-max (T13)
                float mnew = fmaxf(m_run, tmax);
                float r = __builtin_amdgcn_exp2f(m_run - mnew);
                l_run *= r;
                #pragma unroll
                for (int dh = 0; dh < 2; ++dh)
                    #pragma unroll
                    for (int r2 = 0; r2 < 16; ++r2) acc_o[dh][r2] *= r;
                m_run = mnew;
            }
            float ps0 = 0.f, ps1 = 0.f;
            #pragma unroll
            for (int i = 0; i < 8; ++i) {
                float p0 = __builtin_amdgcn_exp2f(s[2 * i]     - m_run);
                float p1 = __builtin_amdgcn_exp2f(s[2 * i + 1] - m_run);
                ps0 += p0; ps1 += p1;
                w0[i] = pkbf(p0, p1);
            }
            float psum = ps0 + ps1;
            psum += __shfl_xor(psum, 32);
            l_run += psum;
        }

        // ---- PV half 0 ----
        #pragma unroll
        for (int t2 = 0; t2 < 2; ++t2) {
            u32x2 r0 = __builtin_amdgcn_permlane32_swap(w0[t2 * 4 + 0], w0[t2 * 4 + 2], false, false);
            u32x2 r1 = __builtin_amdgcn_permlane32_swap(w0[t2 * 4 + 1], w0[t2 * 4 + 3], false, false);
            u32x4 ua = (u32x4){r0[0], r1[0], r0[1], r1[1]};
            bf16x8 pa = *(bf16x8*)&ua;
            #pragma unroll
            for (int dh = 0; dh < 2; ++dh) {
                bf16x8 bv = *(const bf16x8*)&Vt[cur][dh * 32 + l31][t2 * 16 + h * 8];
                acc_o[dh] = __builtin_amdgcn_mfma_f32_32x32x16_bf16(pa, bv, acc_o[dh], 0, 0, 0);
            }
        }

        // ---- softmax half 1 (VALU; overlaps PV h0) ----
        unsigned w1[8];
        {
            float s[16], tmax = -1e30f;
            #pragma unroll
            for (int g = 0; g < 4; ++g) {
                f32x4 mk = *(const f32x4*)&pmL[kt + 32 + g * 8 + h * 4];
                #pragma unroll
                for (int j = 0; j < 4; ++j) {
                    float val = fmaf(a1[g * 4 + j], SC, mk[j]);
                    s[g * 4 + j] = val;
                    tmax = fmaxf(tmax, val);
                }
            }
            tmax = fmaxf(tmax, __shfl_xor(tmax, 32));
            if (__any(tmax > m_run + 8.0f)) {
                float mnew = fmaxf(m_run, tmax);
                float r = __builtin_amdgcn_exp2f(m_run - mnew);
                l_run *= r;
                #pragma unroll
                for (int dh = 0; dh < 2; ++dh)
                    #pragma unroll
                    for (int r2 = 0; r2 < 16; ++r2) acc_o[dh][r2] *= r;
                m_run = mnew;
            }
            float ps0 = 0.f, ps1 = 0.f;
            #pragma unroll
            for (int i = 0; i < 8; ++i) {
                float p0 = __builtin_amdgcn_exp2f(s[2 * i]     - m_run);
                float p1 = __builtin_amdgcn_exp2f(s[2 * i + 1] - m_run);
                ps0 += p0; ps1 += p1;
                w1[i] = pkbf(p0, p1);
            }
            float psum = ps0 + ps1;
            psum += __shfl_xor(psum, 32);
            l_run += psum;
        }

        // ---- PV half 1 ----
        #pragma unroll
        for (int t2 = 0; t2 < 2; ++t2) {
            u32x2 r0 = __builtin_amdgcn_permlane32_swap(w1[t2 * 4 + 0], w1[t2 * 4 + 2], false, false);
            u32x2 r1 = __builtin_amdgcn_permlane32_swap(w1[t2 * 4 + 1], w1[t2 * 4 + 3], false, false);
            u32x4 ua = (u32x4){r0[0], r1[0], r0[1], r1[1]};
            bf16x8 pa = *(bf16x8*)&ua;
            #pragma unroll
            for (int dh = 0; dh < 2; ++dh) {
                bf16x8 bv = *(const bf16x8*)&Vt[cur][dh * 32 + l31][32 + t2 * 16 + h * 8];
                acc_o[dh] = __builtin_amdgcn_mfma_f32_32x32x16_bf16(pa, bv, acc_o[dh], 0, 0, 0);
            }
        }

        if (t < NT - 1) {   // write next tile into alternate buffer
            *(u32x4*)&Klds[cur ^ 1][kk][d0] = (u32x4){pkbf(kA[0], kA[1]), pkbf(kA[2], kA[3]),
                                                      pkbf(kB[0], kB[1]), pkbf(kB[2], kB[3])};
            *(u32x4*)&Vt[cur ^ 1][dcol][kr0] = (u32x4){pkbf(vv[0], vv[1]), pkbf(vv[2], vv[3]),
                                                       pkbf(vv[4], vv[5]), pkbf(vv[6], vv[7])};
        }
        cur ^= 1;
    }

    // ---- channel gate: gate[q][e] = sum_d am[q][d]*W[e][d], same C layout as O ----
    f32x16 acc_g[2];
    #pragma unroll
    for (int eh = 0; eh < 2; ++eh)
        #pragma unroll
        for (int r = 0; r < 16; ++r) acc_g[eh][r] = 0.0f;

    bf16x8 bam[4];
    #pragma unroll
    for (int ds = 0; ds < 4; ++ds) {
        const f32x4* p1 = (const f32x4*)(V1p + (size_t)qrow * D + ds * 16 + h * 8);
        const f32x4* pk = (const f32x4*)(Kp  + (size_t)qrow * D + ds * 16 + h * 8);
        f32x4 a0 = p1[0], a1 = p1[1], c0 = pk[0], c1 = pk[1];
        u32x4 u = (u32x4){pkbf(a0[0]*c0[0], a0[1]*c0[1]), pkbf(a0[2]*c0[2], a0[3]*c0[3]),
                          pkbf(a1[0]*c1[0], a1[1]*c1[1]), pkbf(a1[2]*c1[2], a1[3]*c1[3])};
        bam[ds] = *(bf16x8*)&u;
    }
    #pragma unroll
    for (int eh = 0; eh < 2; ++eh) {
        #pragma unroll
        for (int ds = 0; ds < 4; ++ds) {
            const f32x4* pw = (const f32x4*)(W + (size_t)(eh * 32 + l31) * D + ds * 16 + h * 8);
            f32x4 x0 = pw[0], x1 = pw[1];
            u32x4 u = (u32x4){pkbf(x0[0], x0[1]), pkbf(x0[2], x0[3]),
                              pkbf(x1[0], x1[1]), pkbf(x1[2], x1[3])};
            bf16x8 bw = *(bf16x8*)&u;
            acc_g[eh] = __builtin_amdgcn_mfma_f32_32x32x16_bf16(bam[ds], bw, acc_g[eh], 0, 0, 0);
        }
    }

    // ---- epilogue: out = (O/l) * sigmoid(gate + b) ----
    Lw[wid][l31] = 1.0f / l_run;
    __builtin_amdgcn_wave_barrier();
    const float bv0 = bch[l31], bv1 = bch[32 + l31];
    #pragma unroll
    for (int dh = 0; dh < 2; ++dh) {
        const float bc = dh ? bv1 : bv0;
        #pragma unroll
        for (int r = 0; r < 16; ++r) {
            const int ql = (r & 3) + 8 * (r >> 2) + 4 * h;   // crow(r,h)
            float invl = Lw[wid][ql];
            float o = acc_o[dh][r] * invl;
            float z = acc_g[dh][r] + bc;
            float gate = 1.0f / (1.0f + __expf(-z));
            out_attn[base + (size_t)(q0 + ql) * D + dh * 32 + l31] = o * gate;
        }
    }
}

extern "C" void kernel_launch(void* const* d_in, const int* in_sizes, int n_in,
                              void* d_out, int out_size, void* d_ws, size_t ws_size,
                              hipStream_t stream) {
    const float* gv   = (const float*)d_in[0];
    const float* q2   = (const float*)d_in[1];
    const float* keyp = (const float*)d_in[2];
    const int*   mask = (const int*)  d_in[3];
    const float* v1   = (const float*)d_in[4];
    const float* v2   = (const float*)d_in[5];
    const float* W    = (const float*)d_in[6];
    const float* bch  = (const float*)d_in[7];
    float* out = (float*)d_out;

    int*   vidx    = (int*)d_ws;                   // 8*1024 int
    float* padmask = (float*)(vidx + 8 * 1024);    // 8*1024 f32
    int*   nvalid  = (int*)(padmask + 8 * 1024);   // 8 int

    aoa_prep_kernel<<<8, 1024, 0, stream>>>(mask, vidx, padmask, nvalid);

    dim3 grid(64, 4);   // (b*h, 256-row q-tile) = 256 blocks = 1/CU
    aoa_attn_kernel<<<grid, 512, 0, stream>>>(gv, q2, keyp, v1, v2, W, bch,
                                              vidx, padmask, nvalid, out);
}